// Round 6
// baseline (7576.288 us; speedup 1.0000x reference)
//
#include <hip/hip_runtime.h>

// TrainerRNN: 10-layer GRU (T=2048, IN=384, H=768) + linear head (384).
// ROUND 11: kill the last episodic MALL wait + halve detect quantum.
// R10 = 3.32us/row (~8000cy) with <=1100cy of real work: the row period is
// agent-scope (MALL) store-visibility + tag-detect latency. Two changes:
//  - gi computed TWO rows ahead (register ring gA=gi(t), gB=gi(t+1); tail
//    of row t computes gi(t+2) from (l-1,t+2)). The shadow source now has a
//    full row-period of slack -> never on the critical path, even under
//    jitter. Prologue computes gi(0),gi(1) (waits l-1 rows 0,1; startup
//    only). Back-pressure margin for the t+2 read re-derived: overwrite of
//    slot (t+2)&15 (tag t+19) happens at l-1's row t+18, whose last bp
//    check (rows ===0 mod 4) guarantees ctr[l] >= 24*floor((t+4..6)/4) =>
//    layer l completed >= row t+2 > t => read long done. >=2-row margin.
//  - own-row detect: TWO interleaved reload streams per word (check A /
//    reissue A / check B / reissue B): sampling period ~L/2 instead of L,
//    expected detect ~1.0-1.25 L instead of ~1.5 L.
//  - both LDS h-stages single-buffered: per row, hcs written pre-barrier#1,
//    read after it; next write is after row-t barrier#2. hsd written in the
//    tail (post-store), read after barrier#2; next write after row-t+1
//    barrier#1. Every write-read pair is barrier-separated.
//  - critical path per row: spin(own,2-stream) -> stage hcs -> barrier#1 ->
//    hh GEMV (fp32 reg weights) -> butterfly -> gates(all lanes) -> st64.
//    Tail (hidden under next detect window): sample issue, hsd stage,
//    barrier#2, ih dot2 GEMV -> gi(t+2), gi ring swap, bumps.
// Tag scheme, relaxed AGENT atomics, fp32 hh / fp16 w_ih numerics identical
// to R9/R10.

#define T_SEQ 2048
#define H_DIM 768
#define IN0   384
#define G3    2304
#define NLAYER 10
#define BPL   24                      // blocks per layer
#define NBLK  (NLAYER * BPL)          // 240
#define UPB   32                      // units per block
#define NTHR  512                     // 8 waves x 4 units x 16 lanes
#define NOUT  384
#define CTR_STRIDE 32                 // counters 128 B apart
#define RING  16                      // ring rows per layer
#define WIH_STRIDE 776                // 768 + 8 halves pad (1552B rows)
#define HCS_STRIDE 52                 // 48 + 4 pad floats (208B)
#define HSD_STRIDE 56                 // 48 + 8 pad halves (112B)
#define HSD0_STRIDE 32                // layer-0: 24 + 8 halves (64B)

typedef _Float16 half2_t __attribute__((ext_vector_type(2)));
typedef _Float16 half8_t __attribute__((ext_vector_type(8)));
typedef unsigned long long u64;

__device__ __forceinline__ float sigm(float x) { return 1.0f / (1.0f + __expf(-x)); }

__device__ __forceinline__ u64 ld64(const u64* p) {
    return __hip_atomic_load(p, __ATOMIC_RELAXED, __HIP_MEMORY_SCOPE_AGENT);
}
__device__ __forceinline__ void st64(u64* p, u64 v) {
    __hip_atomic_store(p, v, __ATOMIC_RELAXED, __HIP_MEMORY_SCOPE_AGENT);
}
__device__ __forceinline__ unsigned ldctr(const unsigned* p) {
    return __hip_atomic_load(p, __ATOMIC_RELAXED, __HIP_MEMORY_SCOPE_AGENT);
}
__device__ __forceinline__ unsigned tag_of(u64 u) { return (unsigned)(u >> 32); }
__device__ __forceinline__ float    val_of(u64 u) { return __uint_as_float((unsigned)u); }
__device__ __forceinline__ u64      pack(float v, unsigned t) {
    return ((u64)t << 32) | (u64)__float_as_uint(v);
}

__device__ __forceinline__ float dot8(half8_t h, half8_t w, float acc) {
    union U { half8_t v; unsigned u[4]; };
    U H; H.v = h; U W; W.v = w;
#pragma unroll
    for (int j = 0; j < 4; ++j) {
#if __has_builtin(__builtin_amdgcn_fdot2)
        acc = __builtin_amdgcn_fdot2(__builtin_bit_cast(half2_t, H.u[j]),
                                     __builtin_bit_cast(half2_t, W.u[j]), acc, false);
#else
        half2_t a = __builtin_bit_cast(half2_t, H.u[j]);
        half2_t b = __builtin_bit_cast(half2_t, W.u[j]);
        asm volatile("v_dot2_f32_f16 %0, %1, %2, %0" : "+v"(acc) : "v"(a), "v"(b));
#endif
    }
    return acc;
}

extern "C" __global__ __launch_bounds__(NTHR, 1) void gru_flow(
    const float* __restrict__ x,
    const float* __restrict__ wih0,
    const float* __restrict__ whh0,
    const float* __restrict__ bih0,
    const float* __restrict__ bhh0,
    const float* __restrict__ wihS,
    const float* __restrict__ whhS,
    const float* __restrict__ bihS,
    const float* __restrict__ bhhS,
    u64* __restrict__ ring64,          // 10 layers x RING x 768 x {f32,tag} (zeroed)
    float* __restrict__ h9,            // 2048 x 768 (layer 9 output, plain)
    unsigned int* __restrict__ ctr)    // per-layer progress counters (zeroed)
{
    __shared__ __align__(16) _Float16 wih16[96 * WIH_STRIDE];   // 148,992 B
    __shared__ __align__(16) float    hcs[16 * HCS_STRIDE];     //   3,328 B
    __shared__ __align__(16) _Float16 hsd16[16 * HSD_STRIDE];   //   1,792 B

    const int tid  = threadIdx.x;
    const int lane = tid & 63;
    const int wv   = tid >> 6;         // 0..7
    const int p    = lane & 15;        // k-slice position, 0..15
    const int ulocal = wv * 4 + (lane >> 4);       // 0..31
    const int bid  = blockIdx.x;
    const int layer = bid / BPL;
    const int sub   = bid % BPL;
    const int uglob = sub * UPB + ulocal;          // 0..767
    const int Din   = layer ? H_DIM : IN0;
    const bool w2   = (tid < 256);     // thread also owns word tid+512

    const float* wihL = layer ? wihS + (size_t)(layer - 1) * G3 * H_DIM : wih0;
    const float* whhL = layer ? whhS + (size_t)(layer - 1) * G3 * H_DIM : whh0;
    const float* bihL = layer ? bihS + (size_t)(layer - 1) * G3 : bih0;
    const float* bhhL = layer ? bhhS + (size_t)(layer - 1) * G3 : bhh0;

    // ---- prologue: w_hh -> registers (3 gates x 12 float4 per thread) ----
    float4 wr[3][12];
#pragma unroll
    for (int gate = 0; gate < 3; ++gate) {
        const float4* src = (const float4*)(whhL + (size_t)(uglob + gate * H_DIM) * H_DIM + 48 * p);
#pragma unroll
        for (int i = 0; i < 12; ++i) wr[gate][i] = src[i];
    }
    const float bhr  = bhhL[uglob], bhz = bhhL[uglob + H_DIM], bhn  = bhhL[uglob + 2 * H_DIM];
    const float bir  = bihL[uglob], biz = bihL[uglob + H_DIM], bin_ = bihL[uglob + 2 * H_DIM];

    // ---- prologue: w_ih -> LDS fp16 (8 waves x 12 rows) ----
    for (int rr = 0; rr < 12; ++rr) {
        const int r = wv * 12 + rr;            // 0..95
        const int u = r / 3, G = r % 3;
        const float* src = wihL + (size_t)(sub * UPB + u + G * H_DIM) * Din;
        _Float16* dst = wih16 + r * WIH_STRIDE;
        for (int k = lane; k < Din; k += 64) dst[k] = (_Float16)src[k];
    }
    __syncthreads();

    // ---- spin helpers ----
    auto spin1 = [&](u64 cached, const u64* addr, unsigned tgt) -> u64 {
        u64 v = cached;
        while (tag_of(v) != tgt) v = ld64(addr);
        return v;
    };
    auto spin2 = [&](u64 cached, const u64* addr, unsigned tgt) -> u64 {
        u64 v = cached;
        if (tag_of(v) == tgt) return v;
        u64 v2 = ld64(addr);
        for (;;) {
            v = ld64(addr);
            if (tag_of(v2) == tgt) return v2;
            v2 = ld64(addr);
            if (tag_of(v) == tgt) return v;
        }
    };

    // ---- ih GEMV from hsd16 (fp16 dot2), 16-lane butterfly ----
    auto ih_gemv = [&](float& gr, float& gz, float& gn) {
        float sr = 0.f, sz = 0.f, sn = 0.f;
        if (layer) {
            const half8_t* h8 = (const half8_t*)(hsd16 + p * HSD_STRIDE);
            const half8_t* w0 = (const half8_t*)(wih16 + (ulocal * 3 + 0) * WIH_STRIDE + 48 * p);
            const half8_t* w1 = (const half8_t*)(wih16 + (ulocal * 3 + 1) * WIH_STRIDE + 48 * p);
            const half8_t* wn = (const half8_t*)(wih16 + (ulocal * 3 + 2) * WIH_STRIDE + 48 * p);
#pragma unroll
            for (int i = 0; i < 6; ++i) {
                const half8_t hv = h8[i];
                sr = dot8(hv, w0[i], sr);
                sz = dot8(hv, w1[i], sz);
                sn = dot8(hv, wn[i], sn);
            }
        } else {
            const half8_t* h8 = (const half8_t*)(hsd16 + p * HSD0_STRIDE);
            const half8_t* w0 = (const half8_t*)(wih16 + (ulocal * 3 + 0) * WIH_STRIDE + 24 * p);
            const half8_t* w1 = (const half8_t*)(wih16 + (ulocal * 3 + 1) * WIH_STRIDE + 24 * p);
            const half8_t* wn = (const half8_t*)(wih16 + (ulocal * 3 + 2) * WIH_STRIDE + 24 * p);
#pragma unroll
            for (int i = 0; i < 3; ++i) {
                const half8_t hv = h8[i];
                sr = dot8(hv, w0[i], sr);
                sz = dot8(hv, w1[i], sz);
                sn = dot8(hv, wn[i], sn);
            }
        }
#pragma unroll
        for (int off = 1; off <= 8; off <<= 1) {
            sr += __shfl_xor(sr, off, 64);
            sz += __shfl_xor(sz, off, 64);
            sn += __shfl_xor(sn, off, 64);
        }
        gr = sr + bir; gz = sz + biz; gn = sn + bin_;
    };

    // ---- helpers to stage a 768-word tagged row into hsd16 (fp16) ----
    auto stage_hsd = [&](const u64* sp, unsigned tgt) {
        const u64 a = spin1(0, sp + tid, tgt);
        hsd16[(tid / 48) * HSD_STRIDE + tid % 48] = (_Float16)val_of(a);
        if (w2) {
            const u64 c = spin1(0, sp + tid + 512, tgt);
            hsd16[((tid + 512) / 48) * HSD_STRIDE + (tid + 512) % 48] = (_Float16)val_of(c);
        }
    };

    // ---- prologue: gi(0) -> gA, gi(1) -> gB ----
    float gA_r, gA_z, gA_n, gB_r, gB_z, gB_n;
    if (layer) {
        const u64* base = ring64 + (size_t)(layer - 1) * RING * H_DIM;
        stage_hsd(base, 1u);                         // (l-1, 0)
        __syncthreads();
        ih_gemv(gA_r, gA_z, gA_n);
        __syncthreads();                             // gemv reads done before restage
        stage_hsd(base + H_DIM, 2u);                 // (l-1, 1)
        __syncthreads();
        ih_gemv(gB_r, gB_z, gB_n);
    } else {
        if (tid < IN0) hsd16[(tid / 24) * HSD0_STRIDE + tid % 24] = (_Float16)x[tid];
        __syncthreads();
        ih_gemv(gA_r, gA_z, gA_n);
        __syncthreads();
        if (tid < IN0) hsd16[(tid / 24) * HSD0_STRIDE + tid % 24] = (_Float16)x[IN0 + tid];
        __syncthreads();
        ih_gemv(gB_r, gB_z, gB_n);
    }

    // ---- initial samples: shadow target of row 0's tail = (l-1, 2), tag 3 ----
    u64 ca0 = 0, ca1 = 0, sa0 = 0, sa1 = 0;
    float xs = 0.f;
    if (layer) {
        const u64* sp = ring64 + ((size_t)(layer - 1) * RING + 2) * H_DIM;
        sa0 = ld64(sp + tid);
        if (w2) sa1 = ld64(sp + tid + 512);
    } else if (tid < IN0) {
        xs = x[2 * IN0 + tid];
    }

    unsigned bp = 0;                   // prefetched ctr[layer+1]

    for (int t = 0; t < T_SEQ; ++t) {
        // ---- back-pressure (amortized, register compare; ~never spins) ----
        if (layer != NLAYER - 1 && t >= 16 && (t & 3) == 0) {
            const unsigned tgt = 24u * (unsigned)((t - 12) >> 2);
            while (bp < tgt) {
                __builtin_amdgcn_s_sleep(2);
                bp = ldctr(&ctr[(layer + 1) * CTR_STRIDE]);
            }
        }

        // ---- 1: own-row detect (2-stream spin) + stage hcs ----
        if (t > 0) {
            const u64* hr = ring64 + ((size_t)layer * RING + ((t - 1) & (RING - 1))) * H_DIM;
            const u64 a = spin2(ca0, hr + tid, (unsigned)t);
            hcs[(tid / 48) * HCS_STRIDE + tid % 48] = val_of(a);
            if (w2) {
                const u64 c = spin2(ca1, hr + tid + 512, (unsigned)t);
                hcs[((tid + 512) / 48) * HCS_STRIDE + (tid + 512) % 48] = val_of(c);
            }
        }

        // ---- 2: barrier #1 ----
        __syncthreads();

        // ---- 3: hh GEMV (fp32 reg weights) + butterfly + gates + store ----
        float ar = 0.f, az = 0.f, an = 0.f;
        if (t > 0) {
            const float4* hs = (const float4*)(hcs + p * HCS_STRIDE);
#pragma unroll
            for (int i = 0; i < 12; ++i) {
                const float4 h4 = hs[i];
                ar += h4.x * wr[0][i].x + h4.y * wr[0][i].y + h4.z * wr[0][i].z + h4.w * wr[0][i].w;
                az += h4.x * wr[1][i].x + h4.y * wr[1][i].y + h4.z * wr[1][i].z + h4.w * wr[1][i].w;
                an += h4.x * wr[2][i].x + h4.y * wr[2][i].y + h4.z * wr[2][i].z + h4.w * wr[2][i].w;
            }
        }
#pragma unroll
        for (int off = 1; off <= 8; off <<= 1) {
            ar += __shfl_xor(ar, off, 64);
            az += __shfl_xor(az, off, 64);
            an += __shfl_xor(an, off, 64);
        }
        {
            const float hp = (t > 0) ? hcs[(uglob / 48) * HCS_STRIDE + uglob % 48] : 0.f;
            const float r = sigm(ar + bhr + gA_r);
            const float z = sigm(az + bhz + gA_z);
            const float n = tanhf(gA_n + r * (an + bhn));
            const float hnew = (1.f - z) * n + z * hp;
            if (p == 0) {
                st64(&ring64[((size_t)layer * RING + (t & (RING - 1))) * H_DIM + uglob],
                     pack(hnew, (unsigned)(t + 1)));
                if (layer == NLAYER - 1) h9[(size_t)t * H_DIM + uglob] = hnew;
            }
        }

        // ---- 4: issue next-row samples (own h(t); shadow (l-1,t+3)) ----
        if ((t + 1) < T_SEQ) {
            const u64* hrn = ring64 + ((size_t)layer * RING + (t & (RING - 1))) * H_DIM;
            ca0 = ld64(hrn + tid);
            if (w2) ca1 = ld64(hrn + tid + 512);
            if ((t + 3) < T_SEQ) {
                if (layer) {
                    const u64* spn = ring64 + ((size_t)(layer - 1) * RING + ((t + 3) & (RING - 1))) * H_DIM;
                    sa0 = ld64(spn + tid);
                    if (w2) sa1 = ld64(spn + tid + 512);
                } else if (tid < IN0) {
                    xs = x[(size_t)(t + 3) * IN0 + tid];
                }
            }
        }

        // ---- 5-7: tail (hidden under next row's detect window):
        //      validate shadow (l-1,t+2) tag t+3, stage hsd, barrier#2,
        //      ih GEMV -> gi(t+2) ----
        if ((t + 2) < T_SEQ) {
            if (layer) {
                const u64* sp = ring64 + ((size_t)(layer - 1) * RING + ((t + 2) & (RING - 1))) * H_DIM;
                const u64 a = spin1(sa0, sp + tid, (unsigned)(t + 3));
                hsd16[(tid / 48) * HSD_STRIDE + tid % 48] = (_Float16)val_of(a);
                if (w2) {
                    const u64 c = spin1(sa1, sp + tid + 512, (unsigned)(t + 3));
                    hsd16[((tid + 512) / 48) * HSD_STRIDE + (tid + 512) % 48] = (_Float16)val_of(c);
                }
            } else {
                if (tid < IN0) hsd16[(tid / 24) * HSD0_STRIDE + tid % 24] = (_Float16)xs;
            }
            __syncthreads();                         // barrier #2
            float gn_r, gn_z, gn_n;
            ih_gemv(gn_r, gn_z, gn_n);
            gA_r = gB_r; gA_z = gB_z; gA_n = gB_n;   // gi ring rotate
            gB_r = gn_r; gB_z = gn_z; gB_n = gn_n;
        } else {
            gA_r = gB_r; gA_z = gB_z; gA_n = gB_n;   // last rows: consume gi(t+1)
        }

        // ---- 8: progress bump + back-pressure prefetch (every 4 rows) ----
        if ((t & 3) == 3) {
            if (tid == 0 && layer)
                __hip_atomic_fetch_add(&ctr[layer * CTR_STRIDE], 1u,
                                       __ATOMIC_RELAXED, __HIP_MEMORY_SCOPE_AGENT);
            if (layer != NLAYER - 1)
                bp = ldctr(&ctr[(layer + 1) * CTR_STRIDE]);
        }
    }
}

extern "C" __global__ __launch_bounds__(NOUT, 1) void fc_head(
    const float* __restrict__ h,
    const float* __restrict__ fw,
    const float* __restrict__ fb,
    float* __restrict__ out)
{
    __shared__ float hs[H_DIM];
    const int t = blockIdx.x;
    const float* hr = h + (size_t)t * H_DIM;
    for (int k = threadIdx.x; k < H_DIM; k += NOUT) hs[k] = hr[k];
    __syncthreads();

    const int o = threadIdx.x;
    const float4* wr4 = (const float4*)(fw + (size_t)o * H_DIM);
    const float4* hs4 = (const float4*)hs;
    float acc = fb[o];
#pragma unroll 8
    for (int k = 0; k < H_DIM / 4; ++k) {
        const float4 w = wr4[k], hv = hs4[k];
        acc += w.x * hv.x + w.y * hv.y + w.z * hv.z + w.w * hv.w;
    }
    out[(size_t)t * NOUT + o] = acc;
}

extern "C" void kernel_launch(void* const* d_in, const int* in_sizes, int n_in,
                              void* d_out, int out_size, void* d_ws, size_t ws_size,
                              hipStream_t stream)
{
    const float* x    = (const float*)d_in[0];
    const float* wih0 = (const float*)d_in[1];
    const float* whh0 = (const float*)d_in[2];
    const float* bih0 = (const float*)d_in[3];
    const float* bhh0 = (const float*)d_in[4];
    const float* wihS = (const float*)d_in[5];
    const float* whhS = (const float*)d_in[6];
    const float* bihS = (const float*)d_in[7];
    const float* bhhS = (const float*)d_in[8];
    const float* fcw  = (const float*)d_in[9];
    const float* fcb  = (const float*)d_in[10];

    char* ws = (char*)d_ws;
    unsigned int* ctr = (unsigned int*)ws;                 // 64 KB counter region
    u64* ring64 = (u64*)(ws + 65536);                      // 10*16*768*8 = 983,040 B
    float* h9   = (float*)(ws + 65536 + (size_t)NLAYER * RING * H_DIM * 8); // 2048x768 f32

    hipMemsetAsync(ctr, 0, 65536, stream);
    hipMemsetAsync(ring64, 0, (size_t)NLAYER * RING * H_DIM * 8, stream);  // tag 0 = invalid

    hipLaunchKernelGGL(gru_flow, dim3(NBLK), dim3(NTHR), 0, stream,
                       x, wih0, whh0, bih0, bhh0, wihS, whhS, bihS, bhhS,
                       ring64, h9, ctr);

    hipLaunchKernelGGL(fc_head, dim3(T_SEQ), dim3(NOUT), 0, stream,
                       h9, fcw, fcb, (float*)d_out);
}

// Round 7
// 7046.161 us; speedup vs baseline: 1.0752x; 1.0752x over previous
//
#include <hip/hip_runtime.h>

// TrainerRNN: 10-layer GRU (T=2048, IN=384, H=768) + linear head (384).
// ROUND 12: R10 structure + packed tag-in-mantissa publication.
// R11 (more spin streams, deeper gi pipeline) REGRESSED with lower VALUBusy:
// the row period is partly MALL/HBM contention from ring spin traffic
// (FETCH 612MB vs 140MB of weights => ~470MB is spin/sample loads).
// This round halves the contended traffic at zero numerical cost:
//  - h published as fp32 with the LOW 5 MANTISSA BITS stolen for a tag
//    (t+1)&31 (abs err <= 2^-19 ~ 2e-6), TWO units packed per 8B word:
//    row = 384 words = 3KB (was 768 x 8B = 6KB); spin streams 768 -> 384
//    (one ld64 fetches 2 values + both tags); stores 32 -> 16 per block.
//  - tag aliasing safety: slot s holds rows {s, s+16, s+32, ...}; occupant
//    t vs t-16 tags differ by 16 mod 32 -> distinguishable. memset-0 init
//    has tag 0; tag-0 expectations first occur at t=32 (own, slot 15) and
//    t=30 (shadow, l-1 slot 15), both after slot 15 was written twice
//    (rows 15 tag16, 31 tag0) -> zero-init never falsely accepted.
//  - structure reverted to R10 (best, 7.0ms): single barrier per row,
//    double-buffered hcs/hsd, cached single-stream spins, gi ONE row ahead
//    (R11's extra streams/barriers/regs all regressed).
// Numerics: identical to R10 except <=2e-6 tag-bit noise on the recurrent
// path (h9/fc path stores exact fp32). fp32 hh GEMV (reg weights), fp16
// w_ih + dot2 ih GEMV unchanged. Back-pressure scheme unchanged.

#define T_SEQ 2048
#define H_DIM 768
#define IN0   384
#define G3    2304
#define NLAYER 10
#define BPL   24                      // blocks per layer
#define NBLK  (NLAYER * BPL)          // 240
#define UPB   32                      // units per block
#define NTHR  512                     // 8 waves x 4 units x 16 lanes
#define NOUT  384
#define CTR_STRIDE 32                 // counters 128 B apart
#define RING  16                      // ring rows per layer
#define WPR   384                     // packed words per row (2 units / u64)
#define WIH_STRIDE 776                // 768 + 8 halves pad (1552B rows)
#define HCS_STRIDE 52                 // 48 + 4 pad floats (208B)
#define HSD_STRIDE 56                 // 48 + 8 pad halves (112B)
#define HSD0_STRIDE 32                // layer-0: 24 + 8 halves (64B)

typedef _Float16 half2_t __attribute__((ext_vector_type(2)));
typedef _Float16 half8_t __attribute__((ext_vector_type(8)));
typedef unsigned long long u64;

__device__ __forceinline__ float sigm(float x) { return 1.0f / (1.0f + __expf(-x)); }

__device__ __forceinline__ u64 ld64(const u64* p) {
    return __hip_atomic_load(p, __ATOMIC_RELAXED, __HIP_MEMORY_SCOPE_AGENT);
}
__device__ __forceinline__ void st64(u64* p, u64 v) {
    __hip_atomic_store(p, v, __ATOMIC_RELAXED, __HIP_MEMORY_SCOPE_AGENT);
}
__device__ __forceinline__ unsigned ldctr(const unsigned* p) {
    return __hip_atomic_load(p, __ATOMIC_RELAXED, __HIP_MEMORY_SCOPE_AGENT);
}
// both packed values carry the 5-bit tag in their mantissa LSBs
__device__ __forceinline__ int tagok(u64 v, unsigned tg) {
    return (((unsigned)v & 31u) == tg) & ((((unsigned)(v >> 32)) & 31u) == tg);
}

__device__ __forceinline__ float dot8(half8_t h, half8_t w, float acc) {
    union U { half8_t v; unsigned u[4]; };
    U H; H.v = h; U W; W.v = w;
#pragma unroll
    for (int j = 0; j < 4; ++j) {
#if __has_builtin(__builtin_amdgcn_fdot2)
        acc = __builtin_amdgcn_fdot2(__builtin_bit_cast(half2_t, H.u[j]),
                                     __builtin_bit_cast(half2_t, W.u[j]), acc, false);
#else
        half2_t a = __builtin_bit_cast(half2_t, H.u[j]);
        half2_t b = __builtin_bit_cast(half2_t, W.u[j]);
        asm volatile("v_dot2_f32_f16 %0, %1, %2, %0" : "+v"(acc) : "v"(a), "v"(b));
#endif
    }
    return acc;
}

extern "C" __global__ __launch_bounds__(NTHR, 1) void gru_flow(
    const float* __restrict__ x,
    const float* __restrict__ wih0,
    const float* __restrict__ whh0,
    const float* __restrict__ bih0,
    const float* __restrict__ bhh0,
    const float* __restrict__ wihS,
    const float* __restrict__ whhS,
    const float* __restrict__ bihS,
    const float* __restrict__ bhhS,
    u64* __restrict__ ring64,          // 10 layers x RING x WPR packed (zeroed)
    float* __restrict__ h9,            // 2048 x 768 (layer 9 output, exact fp32)
    unsigned int* __restrict__ ctr)    // per-layer progress counters (zeroed)
{
    __shared__ __align__(16) _Float16 wih16[96 * WIH_STRIDE];       // 148,992 B
    __shared__ __align__(16) float    hcs[2][16 * HCS_STRIDE];      //   6,656 B
    __shared__ __align__(16) _Float16 hsd16[2][16 * HSD_STRIDE];    //   3,584 B

    const int tid  = threadIdx.x;
    const int lane = tid & 63;
    const int wv   = tid >> 6;         // 0..7
    const int p    = lane & 15;        // k-slice position, 0..15
    const int ulocal = wv * 4 + (lane >> 4);       // 0..31
    const int bid  = blockIdx.x;
    const int layer = bid / BPL;
    const int sub   = bid % BPL;
    const int uglob = sub * UPB + ulocal;          // 0..767
    const int Din   = layer ? H_DIM : IN0;

    const float* wihL = layer ? wihS + (size_t)(layer - 1) * G3 * H_DIM : wih0;
    const float* whhL = layer ? whhS + (size_t)(layer - 1) * G3 * H_DIM : whh0;
    const float* bihL = layer ? bihS + (size_t)(layer - 1) * G3 : bih0;
    const float* bhhL = layer ? bhhS + (size_t)(layer - 1) * G3 : bhh0;

    // ---- prologue: w_hh -> registers (3 gates x 12 float4 per thread) ----
    float4 wr[3][12];
#pragma unroll
    for (int gate = 0; gate < 3; ++gate) {
        const float4* src = (const float4*)(whhL + (size_t)(uglob + gate * H_DIM) * H_DIM + 48 * p);
#pragma unroll
        for (int i = 0; i < 12; ++i) wr[gate][i] = src[i];
    }
    const float bhr  = bhhL[uglob], bhz = bhhL[uglob + H_DIM], bhn  = bhhL[uglob + 2 * H_DIM];
    const float bir  = bihL[uglob], biz = bihL[uglob + H_DIM], bin_ = bihL[uglob + 2 * H_DIM];

    // ---- prologue: w_ih -> LDS fp16 (8 waves x 12 rows) ----
    for (int rr = 0; rr < 12; ++rr) {
        const int r = wv * 12 + rr;            // 0..95
        const int u = r / 3, G = r % 3;
        const float* src = wihL + (size_t)(sub * UPB + u + G * H_DIM) * Din;
        _Float16* dst = wih16 + r * WIH_STRIDE;
        for (int k = lane; k < Din; k += 64) dst[k] = (_Float16)src[k];
    }
    __syncthreads();

    // ---- stage helper: packed u64 -> 2 fp16 halves in hsd16[b] ----
    auto stage_hsd = [&](int b, int w, u64 v) {
        const int s = w / 24, idx = (2 * w) % 48;
        const _Float16 a = (_Float16)__uint_as_float((unsigned)v & ~31u);
        const _Float16 c = (_Float16)__uint_as_float((unsigned)(v >> 32) & ~31u);
        const unsigned pk = (unsigned)__builtin_bit_cast(unsigned short, a)
                          | ((unsigned)__builtin_bit_cast(unsigned short, c) << 16);
        *(unsigned*)&hsd16[b][s * HSD_STRIDE + idx] = pk;
    };

    // ---- ih GEMV from hsd16[b] (fp16 dot2), 16-lane butterfly ----
    float gi_r = 0.f, gi_z = 0.f, gi_n = 0.f;
    auto ih_gemv = [&](int b) {
        float sr = 0.f, sz = 0.f, sn = 0.f;
        if (layer) {
            const half8_t* h8 = (const half8_t*)(&hsd16[b][p * HSD_STRIDE]);
            const half8_t* w0 = (const half8_t*)(wih16 + (ulocal * 3 + 0) * WIH_STRIDE + 48 * p);
            const half8_t* w1 = (const half8_t*)(wih16 + (ulocal * 3 + 1) * WIH_STRIDE + 48 * p);
            const half8_t* wn = (const half8_t*)(wih16 + (ulocal * 3 + 2) * WIH_STRIDE + 48 * p);
#pragma unroll
            for (int i = 0; i < 6; ++i) {
                const half8_t hv = h8[i];
                sr = dot8(hv, w0[i], sr);
                sz = dot8(hv, w1[i], sz);
                sn = dot8(hv, wn[i], sn);
            }
        } else {
            const half8_t* h8 = (const half8_t*)(&hsd16[b][p * HSD0_STRIDE]);
            const half8_t* w0 = (const half8_t*)(wih16 + (ulocal * 3 + 0) * WIH_STRIDE + 24 * p);
            const half8_t* w1 = (const half8_t*)(wih16 + (ulocal * 3 + 1) * WIH_STRIDE + 24 * p);
            const half8_t* wn = (const half8_t*)(wih16 + (ulocal * 3 + 2) * WIH_STRIDE + 24 * p);
#pragma unroll
            for (int i = 0; i < 3; ++i) {
                const half8_t hv = h8[i];
                sr = dot8(hv, w0[i], sr);
                sz = dot8(hv, w1[i], sz);
                sn = dot8(hv, wn[i], sn);
            }
        }
#pragma unroll
        for (int off = 1; off <= 8; off <<= 1) {
            sr += __shfl_xor(sr, off, 64);
            sz += __shfl_xor(sz, off, 64);
            sn += __shfl_xor(sn, off, 64);
        }
        gi_r = sr + bir; gi_z = sz + biz; gi_n = sn + bin_;
    };

    // ---- prologue: gi(0) from (l-1, slot 0) tag 1 / x row 0, staged to buf 1 ----
    if (layer) {
        if (tid < WPR) {
            const u64* sp = ring64 + (size_t)(layer - 1) * RING * WPR;
            u64 v = 0;
            while (!tagok(v, 1u)) v = ld64(sp + tid);
            stage_hsd(1, tid, v);
        }
    } else {
        if (tid < IN0) hsd16[1][(tid / 24) * HSD0_STRIDE + tid % 24] = (_Float16)x[tid];
    }
    __syncthreads();
    ih_gemv(1);

    // ---- initial samples: shadow of row 0 = (l-1, slot 1) tag 2 / x row 1 ----
    u64 ca0 = 0, sa0 = 0;
    float xs = 0.f;
    if (tid < WPR) {
        if (layer) sa0 = ld64(ring64 + ((size_t)(layer - 1) * RING + 1) * WPR + tid);
        else       xs  = x[IN0 + tid];
    }

    unsigned bp = 0;                   // prefetched ctr[layer+1]

    for (int t = 0; t < T_SEQ; ++t) {
        const int b = t & 1;
        const bool have_s = (t + 1) < T_SEQ;

        // ---- back-pressure (amortized, register compare; ~never spins) ----
        if (layer != NLAYER - 1 && t >= 16 && (t & 3) == 0) {
            const unsigned tgt = 24u * (unsigned)((t - 12) >> 2);
            while (bp < tgt) {
                __builtin_amdgcn_s_sleep(2);
                bp = ldctr(&ctr[(layer + 1) * CTR_STRIDE]);
            }
        }

        // ---- 1: own h(t-1) detect (cached spin, 384 streams) + stage hcs[b] ----
        if (t > 0 && tid < WPR) {
            const u64* hr = ring64 + ((size_t)layer * RING + ((t - 1) & (RING - 1))) * WPR;
            const unsigned tg = (unsigned)t & 31u;
            u64 v = ca0;
            while (!tagok(v, tg)) v = ld64(hr + tid);
            const int s = tid / 24, idx = (2 * tid) % 48;
            float2 hv;
            hv.x = __uint_as_float((unsigned)v & ~31u);
            hv.y = __uint_as_float((unsigned)(v >> 32) & ~31u);
            *(float2*)&hcs[b][s * HCS_STRIDE + idx] = hv;
        }

        // ---- 2: shadow (l-1, t+1) validate (tag t+2) + stage hsd16[b] ----
        if (have_s) {
            if (layer) {
                if (tid < WPR) {
                    const u64* sp = ring64 + ((size_t)(layer - 1) * RING + ((t + 1) & (RING - 1))) * WPR;
                    const unsigned tg2 = (unsigned)(t + 2) & 31u;
                    u64 v = sa0;
                    while (!tagok(v, tg2)) v = ld64(sp + tid);
                    stage_hsd(b, tid, v);
                }
            } else {
                if (tid < IN0) hsd16[b][(tid / 24) * HSD0_STRIDE + tid % 24] = (_Float16)xs;
            }
        }

        // ---- 3: the row's single barrier ----
        __syncthreads();

        // ---- 4: hh GEMV (fp32 reg weights) + butterfly + gates + packed store ----
        float ar = 0.f, az = 0.f, an = 0.f;
        if (t > 0) {
            const float4* hs = (const float4*)(&hcs[b][p * HCS_STRIDE]);
#pragma unroll
            for (int i = 0; i < 12; ++i) {
                const float4 h4 = hs[i];
                ar += h4.x * wr[0][i].x + h4.y * wr[0][i].y + h4.z * wr[0][i].z + h4.w * wr[0][i].w;
                az += h4.x * wr[1][i].x + h4.y * wr[1][i].y + h4.z * wr[1][i].z + h4.w * wr[1][i].w;
                an += h4.x * wr[2][i].x + h4.y * wr[2][i].y + h4.z * wr[2][i].z + h4.w * wr[2][i].w;
            }
        }
#pragma unroll
        for (int off = 1; off <= 8; off <<= 1) {
            ar += __shfl_xor(ar, off, 64);
            az += __shfl_xor(az, off, 64);
            an += __shfl_xor(an, off, 64);
        }
        {
            const float hp = (t > 0) ? hcs[b][(uglob / 48) * HCS_STRIDE + uglob % 48] : 0.f;
            const float r = sigm(ar + bhr + gi_r);
            const float z = sigm(az + bhz + gi_z);
            const float n = tanhf(gi_n + r * (an + bhn));
            const float hnew = (1.f - z) * n + z * hp;
            const float hpart = __shfl_xor(hnew, 16, 64);   // partner unit's value
            if (p == 0 && (lane & 16) == 0) {               // lanes 0, 32: even units
                const unsigned tg1 = (unsigned)(t + 1) & 31u;
                const unsigned lo = (__float_as_uint(hnew)  & ~31u) | tg1;
                const unsigned hi = (__float_as_uint(hpart) & ~31u) | tg1;
                st64(&ring64[((size_t)layer * RING + (t & (RING - 1))) * WPR + (uglob >> 1)],
                     ((u64)hi << 32) | (u64)lo);
            }
            if (layer == NLAYER - 1 && p == 0) h9[(size_t)t * H_DIM + uglob] = hnew;
        }

        // ---- 5: issue next-row samples (fly under ih_gemv + next detect) ----
        if (have_s && tid < WPR) {
            ca0 = ld64(ring64 + ((size_t)layer * RING + (t & (RING - 1))) * WPR + tid);
            if ((t + 2) < T_SEQ) {
                if (layer) sa0 = ld64(ring64 + ((size_t)(layer - 1) * RING + ((t + 2) & (RING - 1))) * WPR + tid);
                else       xs  = x[(size_t)(t + 2) * IN0 + tid];
            }
        }

        // ---- 6: ih GEMV -> gi(t+1) (reads hsd16[b], behind barrier 3) ----
        if (have_s) ih_gemv(b);

        // ---- 7: progress bump + back-pressure prefetch (every 4 rows) ----
        if ((t & 3) == 3) {
            if (tid == 0 && layer)
                __hip_atomic_fetch_add(&ctr[layer * CTR_STRIDE], 1u,
                                       __ATOMIC_RELAXED, __HIP_MEMORY_SCOPE_AGENT);
            if (layer != NLAYER - 1)
                bp = ldctr(&ctr[(layer + 1) * CTR_STRIDE]);
        }
    }
}

extern "C" __global__ __launch_bounds__(NOUT, 1) void fc_head(
    const float* __restrict__ h,
    const float* __restrict__ fw,
    const float* __restrict__ fb,
    float* __restrict__ out)
{
    __shared__ float hs[H_DIM];
    const int t = blockIdx.x;
    const float* hr = h + (size_t)t * H_DIM;
    for (int k = threadIdx.x; k < H_DIM; k += NOUT) hs[k] = hr[k];
    __syncthreads();

    const int o = threadIdx.x;
    const float4* wr4 = (const float4*)(fw + (size_t)o * H_DIM);
    const float4* hs4 = (const float4*)hs;
    float acc = fb[o];
#pragma unroll 8
    for (int k = 0; k < H_DIM / 4; ++k) {
        const float4 w = wr4[k], hv = hs4[k];
        acc += w.x * hv.x + w.y * hv.y + w.z * hv.z + w.w * hv.w;
    }
    out[(size_t)t * NOUT + o] = acc;
}

extern "C" void kernel_launch(void* const* d_in, const int* in_sizes, int n_in,
                              void* d_out, int out_size, void* d_ws, size_t ws_size,
                              hipStream_t stream)
{
    const float* x    = (const float*)d_in[0];
    const float* wih0 = (const float*)d_in[1];
    const float* whh0 = (const float*)d_in[2];
    const float* bih0 = (const float*)d_in[3];
    const float* bhh0 = (const float*)d_in[4];
    const float* wihS = (const float*)d_in[5];
    const float* whhS = (const float*)d_in[6];
    const float* bihS = (const float*)d_in[7];
    const float* bhhS = (const float*)d_in[8];
    const float* fcw  = (const float*)d_in[9];
    const float* fcb  = (const float*)d_in[10];

    char* ws = (char*)d_ws;
    unsigned int* ctr = (unsigned int*)ws;                 // 64 KB counter region
    u64* ring64 = (u64*)(ws + 65536);                      // 10*16*384*8 = 491,520 B
    float* h9   = (float*)(ws + 65536 + (size_t)NLAYER * RING * WPR * 8); // 2048x768 f32

    hipMemsetAsync(ctr, 0, 65536, stream);
    hipMemsetAsync(ring64, 0, (size_t)NLAYER * RING * WPR * 8, stream);   // tag 0 = invalid

    hipLaunchKernelGGL(gru_flow, dim3(NBLK), dim3(NTHR), 0, stream,
                       x, wih0, whh0, bih0, bhh0, wihS, whhS, bihS, bhhS,
                       ring64, h9, ctr);

    hipLaunchKernelGGL(fc_head, dim3(T_SEQ), dim3(NOUT), 0, stream,
                       h9, fcw, fcb, (float*)d_out);
}